// Round 13
// baseline (194.827 us; speedup 1.0000x reference)
//
#include <hip/hip_runtime.h>
#include <hip/hip_bf16.h>
#include <math.h>

#define HW 12544
#define CC 128
#define BB 4

typedef short bf16x8 __attribute__((ext_vector_type(8)));
typedef float f32x4 __attribute__((ext_vector_type(4)));

__device__ __forceinline__ float bf2f(unsigned int u) {
  union { unsigned int i; float f; } v; v.i = u << 16; return v.f;
}
__device__ __forceinline__ unsigned short f2bf(float f) {
  __hip_bfloat16 h = __float2bfloat16(f);
  return *reinterpret_cast<unsigned short*>(&h);
}
__device__ __forceinline__ float gelu(float v) {
  return 0.5f * v * (1.f + erff(v * 0.70710678118654752f));
}
__device__ __forceinline__ unsigned uc4(const uint4& v, int q) {
  return q == 0 ? v.x : q == 1 ? v.y : q == 2 ? v.z : v.w;
}

// ---- x NCHW fp32 -> xh NHWC bf16 ----
__global__ __launch_bounds__(256) void to_nhwc(const float* __restrict__ x,
                                               unsigned short* __restrict__ xh) {
  const int pt = blockIdx.x, ct = blockIdx.y, b = blockIdx.z;
  const int p0 = pt * 32, c0 = ct * 32;
  const int tid = threadIdx.x;
  __shared__ float ls[32][33];
  int col = tid & 31, r = tid >> 5;
#pragma unroll
  for (int i = 0; i < 4; i++) {
    int c = c0 + r + i * 8;
    ls[r + i * 8][col] = x[((size_t)(b * CC) + c) * HW + p0 + col];
  }
  __syncthreads();
  int px = tid >> 3, cq = (tid & 7) * 4;
  ushort4 v;
  v.x = f2bf(ls[cq + 0][px]);
  v.y = f2bf(ls[cq + 1][px]);
  v.z = f2bf(ls[cq + 2][px]);
  v.w = f2bf(ls[cq + 3][px]);
  *(ushort4*)&xh[((size_t)(b * HW) + p0 + px) * CC + c0 + cq] = v;
}

// ---- pack all 4 weight tensors -> fragment-line layouts ----
__global__ void pack_all(const float* __restrict__ wd1, const float* __restrict__ wo1,
                         const float* __restrict__ wd2, const float* __restrict__ wo2,
                         unsigned short* __restrict__ wpk1, unsigned short* __restrict__ wopk1,
                         unsigned short* __restrict__ wpk2, unsigned short* __restrict__ wopk2) {
  int i = blockIdx.x * 256 + threadIdx.x;   // 368640
  if (i < 294912) {
    int ii = (i < 147456) ? i : i - 147456;
    const float* src = (i < 147456) ? wd1 : wd2;
    unsigned short* dst = (i < 147456) ? wpk1 : wpk2;
    int j = ii & 7, lane = (ii >> 3) & 63, ks = (ii >> 9) & 3, mo = (ii >> 11) & 7, k2 = ii >> 14;
    int o = mo * 16 + (lane & 15), c = ks * 32 + ((lane >> 4) << 3) + j;
    dst[ii] = f2bf(src[(o * CC + c) * 9 + k2]);
  } else {
    int ii = i - 294912;   // 0..73727
    const float* src = (ii < 36864) ? wo1 : wo2;
    unsigned short* dst = (ii < 36864) ? wopk1 : wopk2;
    ii = (ii < 36864) ? ii : ii - 36864;
    int j = ii & 7, lane = (ii >> 3) & 63, ks = (ii >> 9) & 3, mo = (ii >> 11) & 1, k2 = ii >> 12;
    int o = mo * 16 + (lane & 15), c = ks * 32 + ((lane >> 4) << 3) + j;
    dst[ii] = (o < 18) ? f2bf(src[(o * CC + c) * 9 + k2]) : (unsigned short)0;
  }
}

// ---- offset conv via MFMA: 32-px tile (UNCHANGED from verified R12) ----
__global__ __launch_bounds__(256) void offset_mfma(
    const unsigned short* __restrict__ xh, const unsigned short* __restrict__ wopk,
    const float* __restrict__ boff, float* __restrict__ offs2) {
  const int bid0 = blockIdx.x;
  const int bid = (bid0 & 7) * 196 + (bid0 >> 3);   // XCD swizzle, 1568%8==0
  const int b = bid / 392;
  const int p0 = (bid % 392) * 32;
  const int tid = threadIdx.x;
  const int l = tid & 63, w = tid >> 6;
  const int hl = l & 15, ph = l >> 4;
  const int row = l & 15, grp = l >> 4;
  const int pxg = (w >> 1) * 16;    // MFMA pixel-group base
  const int mw = w & 1;             // owned m-fragment
  __shared__ unsigned short s_smp[2][4096];
  const unsigned short* xb = xh + (size_t)b * HW * CC + hl * 8;
  f32x4 acc = (f32x4){0.f, 0.f, 0.f, 0.f};
  uint4 g2[2];
  bf16x8 af[4];

#define OISSUE(K2T)                                                            \
  {                                                                            \
    int ky = (K2T) / 3, kx = (K2T) % 3;                                        \
    _Pragma("unroll") for (int s = 0; s < 2; s++) {                            \
      int pxl = w * 8 + s * 4 + ph;                                            \
      int p = p0 + pxl;                                                        \
      int ho = p / 112, wo = p - ho * 112;                                     \
      int y = ho + ky - 1, x = wo + kx - 1;                                    \
      uint4 t = make_uint4(0u, 0u, 0u, 0u);                                    \
      if (((unsigned)y < 112u) & ((unsigned)x < 112u))                         \
        t = *(const uint4*)&xb[(size_t)(y * 112 + x) * CC];                    \
      g2[s] = t;                                                               \
    }                                                                          \
  }

#define OCOMMIT(BNBUF)                                                         \
  _Pragma("unroll") for (int s = 0; s < 2; s++) {                              \
    int pxl = w * 8 + s * 4 + ph;                                              \
    *(uint4*)((char*)&s_smp[BNBUF][0] +                                        \
              ((pxl * 256 + hl * 16) ^ ((pxl & 7) << 4))) = g2[s];             \
  }

#define OMFMA(BCBUF, ksB)                                                      \
  __builtin_amdgcn_s_setprio(1);                                               \
  _Pragma("unroll") for (int ks = ksB; ks < ksB + 2; ks++) {                   \
    int pxr = pxg + row;                                                       \
    bf16x8 bfr = *(const bf16x8*)((const char*)&s_smp[BCBUF][0] +              \
                 ((pxr * 256 + ks * 64 + grp * 16) ^ ((pxr & 7) << 4)));       \
    acc = __builtin_amdgcn_mfma_f32_16x16x32_bf16(af[ks], bfr, acc, 0, 0, 0);  \
  }                                                                            \
  __builtin_amdgcn_s_setprio(0);

#define OLOADW(K2T)                                                            \
  {                                                                            \
    const unsigned short* wb = wopk + (size_t)(K2T) * 4096;                    \
    _Pragma("unroll") for (int ks = 0; ks < 4; ks++)                           \
      af[ks] = *(const bf16x8*)&wb[(mw * 4 + ks) * 512 + l * 8];               \
  }

#define OITER(K2T, BC, BN)                                                     \
  {                                                                            \
    if ((K2T) < 8) { OISSUE((K2T) + 1); }                                      \
    OMFMA(BC, 0);                                                              \
    if ((K2T) < 8) { OCOMMIT(BN); }                                            \
    OMFMA(BC, 2);                                                              \
    if ((K2T) < 8) { OLOADW((K2T) + 1); __syncthreads(); }                     \
  }

  OISSUE(0); OCOMMIT(0); OLOADW(0);
  __syncthreads();
  OITER(0, 0, 1) OITER(1, 1, 0) OITER(2, 0, 1) OITER(3, 1, 0) OITER(4, 0, 1)
  OITER(5, 1, 0) OITER(6, 0, 1) OITER(7, 1, 0) OITER(8, 0, 1)
#undef OISSUE
#undef OCOMMIT
#undef OMFMA
#undef OLOADW
#undef OITER

  int p = p0 + pxg + row;
  if (mw == 0) {
    float2 w0 = make_float2(acc[0] + boff[grp * 4 + 0], acc[1] + boff[grp * 4 + 1]);
    float2 w1 = make_float2(acc[2] + boff[grp * 4 + 2], acc[3] + boff[grp * 4 + 3]);
    *(float2*)&offs2[((size_t)(b * 9 + grp * 2) * HW + p) * 2] = w0;
    *(float2*)&offs2[((size_t)(b * 9 + grp * 2 + 1) * HW + p) * 2] = w1;
  } else if (grp == 0) {
    float2 w2 = make_float2(acc[0] + boff[16], acc[1] + boff[17]);
    *(float2*)&offs2[((size_t)(b * 9 + 8) * HW + p) * 2] = w2;
  }
}

// ---- deformable conv via MFMA: 16-px tile (3136 blocks = 4x TLP vs R10) ----
__global__ __launch_bounds__(256, 3) void deform_mfma(
    const unsigned short* __restrict__ xh, const float* __restrict__ offs2,
    const unsigned short* __restrict__ wpk, unsigned short* __restrict__ zh,
    float* __restrict__ part) {
  const int bid0 = blockIdx.x;
  const int bid = (bid0 & 7) * 392 + (bid0 >> 3);   // XCD swizzle, 3136%8==0
  const int b = bid / 784;
  const int p0 = (bid % 784) * 16;
  const int tid = threadIdx.x;
  const int l = tid & 63, w = tid >> 6;
  const int hl = l & 15, ph = l >> 4;
  const int row = l & 15, grp = l >> 4;
  __shared__ unsigned short s_smp[2][2048];       // 8192 B (16px x 128ch, dbuf)
  __shared__ uint4 s_coord[9][16];                // 2304 B

  // coord precompute: clamped u16 corner indices + bf16 corner weights
  for (int e = tid; e < 144; e += 256) {
    int k2 = e >> 4, px = e & 15;
    int p = p0 + px;
    int ho = p / 112, wo = p - ho * 112;
    int ky = k2 / 3, kx = k2 - 3 * ky;
    float2 dv = *(const float2*)&offs2[((size_t)(b * 9 + k2) * HW + p) * 2];
    float py = (float)(ho + ky - 1) + dv.x;
    float pxf = (float)(wo + kx - 1) + dv.y;
    float y0f = floorf(py), x0f = floorf(pxf);
    float wy = py - y0f, wx = pxf - x0f;
    int y0 = (int)y0f, x0 = (int)x0f;
    int y1 = y0 + 1, x1 = x0 + 1;
    bool iy0 = ((unsigned)y0 < 112u), iy1 = ((unsigned)y1 < 112u);
    bool ix0 = ((unsigned)x0 < 112u), ix1 = ((unsigned)x1 < 112u);
    float v00 = (iy0 & ix0) ? (1.f - wy) * (1.f - wx) : 0.f;
    float v01 = (iy0 & ix1) ? (1.f - wy) * wx : 0.f;
    float v10 = (iy1 & ix0) ? wy * (1.f - wx) : 0.f;
    float v11 = (iy1 & ix1) ? wy * wx : 0.f;
    int y0c = min(max(y0, 0), 111), y1c = min(max(y1, 0), 111);
    int x0c = min(max(x0, 0), 111), x1c = min(max(x1, 0), 111);
    uint4 ce;
    ce.x = (unsigned)(y0c * 112 + x0c) | ((unsigned)(y0c * 112 + x1c) << 16);
    ce.y = (unsigned)(y1c * 112 + x0c) | ((unsigned)(y1c * 112 + x1c) << 16);
    ce.z = (unsigned)f2bf(v00) | ((unsigned)f2bf(v01) << 16);
    ce.w = (unsigned)f2bf(v10) | ((unsigned)f2bf(v11) << 16);
    s_coord[k2][px] = ce;
  }

  const unsigned short* xb = xh + (size_t)b * HW * CC + hl * 8;
  f32x4 acc[2];
  acc[0] = (f32x4){0.f, 0.f, 0.f, 0.f};
  acc[1] = (f32x4){0.f, 0.f, 0.f, 0.f};
  uint4 g[4];
  uint2 wts;
  bf16x8 af[2][4];
  __syncthreads();

#define DISSUE(K2T)                                                            \
  {                                                                            \
    int pxl = w * 4 + ph;                                                      \
    uint4 cc = s_coord[K2T][pxl];                                              \
    wts = make_uint2(cc.z, cc.w);                                              \
    g[0] = *(const uint4*)&xb[(size_t)(cc.x & 0xffffu) * CC];                  \
    g[1] = *(const uint4*)&xb[(size_t)(cc.x >> 16) * CC];                      \
    g[2] = *(const uint4*)&xb[(size_t)(cc.y & 0xffffu) * CC];                  \
    g[3] = *(const uint4*)&xb[(size_t)(cc.y >> 16) * CC];                      \
  }

#define DCOMMIT(BNBUF)                                                         \
  {                                                                            \
    int pxl = w * 4 + ph;                                                      \
    float w00 = bf2f(wts.x & 0xffffu), w01 = bf2f(wts.x >> 16);                \
    float w10 = bf2f(wts.y & 0xffffu), w11 = bf2f(wts.y >> 16);                \
    unsigned rr[4];                                                            \
    _Pragma("unroll") for (int q = 0; q < 4; q++) {                            \
      unsigned a0 = uc4(g[0], q), a1 = uc4(g[1], q);                           \
      unsigned a2 = uc4(g[2], q), a3 = uc4(g[3], q);                           \
      float elo = w00 * bf2f(a0 & 0xffffu) + w01 * bf2f(a1 & 0xffffu)          \
                + w10 * bf2f(a2 & 0xffffu) + w11 * bf2f(a3 & 0xffffu);         \
      float ehi = w00 * bf2f(a0 >> 16) + w01 * bf2f(a1 >> 16)                  \
                + w10 * bf2f(a2 >> 16) + w11 * bf2f(a3 >> 16);                 \
      rr[q] = (unsigned)f2bf(elo) | ((unsigned)f2bf(ehi) << 16);               \
    }                                                                          \
    *(uint4*)((char*)&s_smp[BNBUF][0] +                                        \
              ((pxl * 256 + hl * 16) ^ ((pxl & 7) << 4))) =                    \
        make_uint4(rr[0], rr[1], rr[2], rr[3]);                                \
  }

#define DMFMA(BCBUF, ksB)                                                      \
  __builtin_amdgcn_s_setprio(1);                                               \
  _Pragma("unroll") for (int ks = ksB; ks < ksB + 2; ks++) {                   \
    bf16x8 bfr = *(const bf16x8*)((const char*)&s_smp[BCBUF][0] +              \
               ((row * 256 + ks * 64 + grp * 16) ^ ((row & 7) << 4)));         \
    _Pragma("unroll") for (int m = 0; m < 2; m++)                              \
      acc[m] = __builtin_amdgcn_mfma_f32_16x16x32_bf16(af[m][ks], bfr, acc[m], 0, 0, 0); \
  }                                                                            \
  __builtin_amdgcn_s_setprio(0);

#define DLOADW(K2T)                                                            \
  {                                                                            \
    const unsigned short* wb = wpk + (size_t)((K2T) * 8 + w * 2) * 2048;       \
    _Pragma("unroll") for (int m = 0; m < 2; m++)                              \
      _Pragma("unroll") for (int ks = 0; ks < 4; ks++)                         \
        af[m][ks] = *(const bf16x8*)&wb[(m * 4 + ks) * 512 + l * 8];           \
  }

#define DITER(K2T, BC, BN)                                                     \
  {                                                                            \
    if ((K2T) < 8) { DISSUE((K2T) + 1); }                                      \
    DMFMA(BC, 0);                                                              \
    if ((K2T) < 8) { DCOMMIT(BN); }                                            \
    DMFMA(BC, 2);                                                              \
    if ((K2T) < 8) { DLOADW((K2T) + 1); __syncthreads(); }                     \
  }

  DISSUE(0); DCOMMIT(0); DLOADW(0);
  __syncthreads();
  DITER(0, 0, 1) DITER(1, 1, 0) DITER(2, 0, 1) DITER(3, 1, 0) DITER(4, 0, 1)
  DITER(5, 1, 0) DITER(6, 0, 1) DITER(7, 1, 0) DITER(8, 0, 1)
#undef DISSUE
#undef DCOMMIT
#undef DMFMA
#undef DLOADW
#undef DITER

  // z write (bf16 NHWC)
#pragma unroll
  for (int m = 0; m < 2; m++) {
    int o = (w * 2 + m) * 16 + grp * 4;
    size_t px = (size_t)(b * HW) + p0 + row;
    unsigned lo = (unsigned)f2bf(acc[m][0]) | ((unsigned)f2bf(acc[m][1]) << 16);
    unsigned hi = (unsigned)f2bf(acc[m][2]) | ((unsigned)f2bf(acc[m][3]) << 16);
    *(uint2*)&zh[px * CC + o] = make_uint2(lo, hi);
  }

  // fused BN partials: per-channel sum/sumsq over this block's 16 px
  float sv[8], qv[8];
#pragma unroll
  for (int m = 0; m < 2; m++)
#pragma unroll
    for (int r = 0; r < 4; r++) {
      float v = acc[m][r];
      sv[m * 4 + r] = v;
      qv[m * 4 + r] = v * v;
    }
#pragma unroll
  for (int d = 1; d < 16; d <<= 1)
#pragma unroll
    for (int i = 0; i < 8; i++) {
      sv[i] += __shfl_xor(sv[i], d);
      qv[i] += __shfl_xor(qv[i], d);
    }
  if (row == 0) {
#pragma unroll
    for (int m = 0; m < 2; m++)
#pragma unroll
      for (int r = 0; r < 4; r++) {
        int ch = (w * 2 + m) * 16 + grp * 4 + r;
        part[(size_t)ch * 3136 + bid] = sv[m * 4 + r];
        part[(size_t)(128 + ch) * 3136 + bid] = qv[m * 4 + r];
      }
  }
}

// ---- BN stats: reduce 3136 block partials per channel ----
__global__ __launch_bounds__(256) void bn_fin(const float* __restrict__ part,
                                              const float* __restrict__ gamma,
                                              const float* __restrict__ beta,
                                              float* __restrict__ stats) {
  const int c = blockIdx.x, t = threadIdx.x;
  float s = 0.f, q = 0.f;
  for (int j = t; j < 3136; j += 256) {
    s += part[(size_t)c * 3136 + j];
    q += part[(size_t)(128 + c) * 3136 + j];
  }
  __shared__ float ss[256], sq2[256];
  ss[t] = s; sq2[t] = q;
  __syncthreads();
  for (int d = 128; d > 0; d >>= 1) {
    if (t < d) { ss[t] += ss[t + d]; sq2[t] += sq2[t + d]; }
    __syncthreads();
  }
  if (t == 0) {
    float N = 50176.f;
    float m = ss[0] / N;
    float var = sq2[0] / N - m * m;
    stats[c] = m;
    stats[128 + c] = rsqrtf(var + 1e-5f) * gamma[c];
    stats[256 + c] = beta[c];
  }
}

// ---- BN+GELU, z bf16 NHWC -> y bf16 NHWC (feeds block 2) ----
__global__ __launch_bounds__(256) void bn_gelu_to_bf16(
    const unsigned short* __restrict__ zh, const float* __restrict__ stats,
    unsigned short* __restrict__ yh) {
  int i = blockIdx.x * 256 + threadIdx.x;   // 802816 exact
  int c0 = (i & 15) * 8;
  uint4 zv = ((const uint4*)zh)[i];
  f32x4 m0 = *(const f32x4*)&stats[c0], m1 = *(const f32x4*)&stats[c0 + 4];
  f32x4 r0 = *(const f32x4*)&stats[128 + c0], r1 = *(const f32x4*)&stats[128 + c0 + 4];
  f32x4 b0 = *(const f32x4*)&stats[256 + c0], b1 = *(const f32x4*)&stats[256 + c0 + 4];
  float v[8] = {bf2f(zv.x & 0xffffu), bf2f(zv.x >> 16), bf2f(zv.y & 0xffffu), bf2f(zv.y >> 16),
                bf2f(zv.z & 0xffffu), bf2f(zv.z >> 16), bf2f(zv.w & 0xffffu), bf2f(zv.w >> 16)};
  unsigned o[4];
#pragma unroll
  for (int j = 0; j < 4; j++) {
    float mj0 = (j < 2) ? m0[j * 2] : m1[j * 2 - 4], mj1 = (j < 2) ? m0[j * 2 + 1] : m1[j * 2 - 3];
    float rj0 = (j < 2) ? r0[j * 2] : r1[j * 2 - 4], rj1 = (j < 2) ? r0[j * 2 + 1] : r1[j * 2 - 3];
    float bj0 = (j < 2) ? b0[j * 2] : b1[j * 2 - 4], bj1 = (j < 2) ? b0[j * 2 + 1] : b1[j * 2 - 3];
    float e0 = gelu((v[j * 2] - mj0) * rj0 + bj0);
    float e1 = gelu((v[j * 2 + 1] - mj1) * rj1 + bj1);
    o[j] = (unsigned)f2bf(e0) | ((unsigned)f2bf(e1) << 16);
  }
  ((uint4*)yh)[i] = make_uint4(o[0], o[1], o[2], o[3]);
}

// ---- final: BN+GELU on z2 bf16 NHWC, transpose to NCHW, +residual x ----
__global__ __launch_bounds__(256) void bn_gelu_final(
    const unsigned short* __restrict__ zh, const float* __restrict__ stats,
    const float* __restrict__ x, float* __restrict__ out) {
  const int pt = blockIdx.x, b = blockIdx.y;
  const int p0 = pt * 16;
  const int tid = threadIdx.x;
  __shared__ float ls[16][129];
  {
    int cq = tid & 15, r = tid >> 4;
    uint4 zv = *(const uint4*)&zh[((size_t)(b * HW) + p0 + r) * CC + cq * 8];
    float v[8] = {bf2f(zv.x & 0xffffu), bf2f(zv.x >> 16), bf2f(zv.y & 0xffffu), bf2f(zv.y >> 16),
                  bf2f(zv.z & 0xffffu), bf2f(zv.z >> 16), bf2f(zv.w & 0xffffu), bf2f(zv.w >> 16)};
    f32x4 m0 = *(const f32x4*)&stats[cq * 8], m1 = *(const f32x4*)&stats[cq * 8 + 4];
    f32x4 r0 = *(const f32x4*)&stats[128 + cq * 8], r1 = *(const f32x4*)&stats[128 + cq * 8 + 4];
    f32x4 b0 = *(const f32x4*)&stats[256 + cq * 8], b1 = *(const f32x4*)&stats[256 + cq * 8 + 4];
#pragma unroll
    for (int j = 0; j < 4; j++) {
      ls[r][cq * 8 + j] = gelu((v[j] - m0[j]) * r0[j] + b0[j]);
      ls[r][cq * 8 + 4 + j] = gelu((v[4 + j] - m1[j]) * r1[j] + b1[j]);
    }
  }
  __syncthreads();
  int c = tid & 127, half = tid >> 7;
  const float* xr = x + ((size_t)(b * CC) + c) * HW + p0 + half * 8;
  float* orow = out + ((size_t)(b * CC) + c) * HW + p0 + half * 8;
  float4 o1 = make_float4(ls[half * 8 + 0][c], ls[half * 8 + 1][c],
                          ls[half * 8 + 2][c], ls[half * 8 + 3][c]);
  float4 o2 = make_float4(ls[half * 8 + 4][c], ls[half * 8 + 5][c],
                          ls[half * 8 + 6][c], ls[half * 8 + 7][c]);
  float4 x1 = *(const float4*)&xr[0];
  float4 x2 = *(const float4*)&xr[4];
  o1.x += x1.x; o1.y += x1.y; o1.z += x1.z; o1.w += x1.w;
  o2.x += x2.x; o2.y += x2.y; o2.z += x2.z; o2.w += x2.w;
  *(float4*)&orow[0] = o1;
  *(float4*)&orow[4] = o2;
}

extern "C" void kernel_launch(void* const* d_in, const int* in_sizes, int n_in,
                              void* d_out, int out_size, void* d_ws, size_t ws_size,
                              hipStream_t stream) {
  const float* x = (const float*)d_in[0];
  const float* w_off1 = (const float*)d_in[1];
  const float* b_off1 = (const float*)d_in[2];
  const float* w_def1 = (const float*)d_in[3];
  const float* gamma1 = (const float*)d_in[4];
  const float* beta1 = (const float*)d_in[5];
  const float* w_off2 = (const float*)d_in[6];
  const float* b_off2 = (const float*)d_in[7];
  const float* w_def2 = (const float*)d_in[8];
  const float* gamma2 = (const float*)d_in[9];
  const float* beta2 = (const float*)d_in[10];
  float* out = (float*)d_out;

  char* ws = (char*)d_ws;
  unsigned short* xhb = (unsigned short*)ws;                  // 12,845,056 B (x NHWC bf16, later y1h)
  unsigned short* zhb = (unsigned short*)(ws + 12845056);     // 12,845,056 B (z bf16 NHWC)
  float* offb = (float*)(ws + 25690112);                      //  3,612,672 B
  unsigned short* wpk1 = (unsigned short*)(ws + 29302784);    //    294,912 B
  unsigned short* wpk2 = (unsigned short*)(ws + 29597696);    //    294,912 B
  unsigned short* wopk1 = (unsigned short*)(ws + 29892608);   //     73,728 B
  unsigned short* wopk2 = (unsigned short*)(ws + 29966336);   //     73,728 B
  float* partb = (float*)(ws + 30040064);                     //  3,211,264 B (256 ch x 3136)
  float* statsb = (float*)(ws + 33251328);                    //      1,536 B

  to_nhwc<<<dim3(392, 4, 4), 256, 0, stream>>>(x, xhb);
  pack_all<<<1440, 256, 0, stream>>>(w_def1, w_off1, w_def2, w_off2,
                                     wpk1, wopk1, wpk2, wopk2);

  // ---- block 1 ----
  offset_mfma<<<1568, 256, 0, stream>>>(xhb, wopk1, b_off1, offb);
  deform_mfma<<<3136, 256, 0, stream>>>(xhb, offb, wpk1, zhb, partb);
  bn_fin<<<128, 256, 0, stream>>>(partb, gamma1, beta1, statsb);
  bn_gelu_to_bf16<<<3136, 256, 0, stream>>>(zhb, statsb, xhb);

  // ---- block 2 ----
  offset_mfma<<<1568, 256, 0, stream>>>(xhb, wopk2, b_off2, offb);
  deform_mfma<<<3136, 256, 0, stream>>>(xhb, offb, wpk2, zhb, partb);
  bn_fin<<<128, 256, 0, stream>>>(partb, gamma2, beta2, statsb);
  bn_gelu_final<<<dim3(784, 4), 256, 0, stream>>>(zhb, statsb, x, out);
}

// Round 14
// 171.724 us; speedup vs baseline: 1.1345x; 1.1345x over previous
//
#include <hip/hip_runtime.h>
#include <hip/hip_bf16.h>
#include <math.h>

#define HW 12544
#define CC 128
#define BB 4

typedef short bf16x8 __attribute__((ext_vector_type(8)));
typedef float f32x4 __attribute__((ext_vector_type(4)));

__device__ __forceinline__ float bf2f(unsigned int u) {
  union { unsigned int i; float f; } v; v.i = u << 16; return v.f;
}
__device__ __forceinline__ unsigned short f2bf(float f) {
  __hip_bfloat16 h = __float2bfloat16(f);
  return *reinterpret_cast<unsigned short*>(&h);
}
__device__ __forceinline__ float gelu(float v) {
  return 0.5f * v * (1.f + erff(v * 0.70710678118654752f));
}
__device__ __forceinline__ unsigned uc4(const uint4& v, int q) {
  return q == 0 ? v.x : q == 1 ? v.y : q == 2 ? v.z : v.w;
}

// ---- x NCHW fp32 -> xh NHWC bf16 ----
__global__ __launch_bounds__(256) void to_nhwc(const float* __restrict__ x,
                                               unsigned short* __restrict__ xh) {
  const int pt = blockIdx.x, ct = blockIdx.y, b = blockIdx.z;
  const int p0 = pt * 32, c0 = ct * 32;
  const int tid = threadIdx.x;
  __shared__ float ls[32][33];
  int col = tid & 31, r = tid >> 5;
#pragma unroll
  for (int i = 0; i < 4; i++) {
    int c = c0 + r + i * 8;
    ls[r + i * 8][col] = x[((size_t)(b * CC) + c) * HW + p0 + col];
  }
  __syncthreads();
  int px = tid >> 3, cq = (tid & 7) * 4;
  ushort4 v;
  v.x = f2bf(ls[cq + 0][px]);
  v.y = f2bf(ls[cq + 1][px]);
  v.z = f2bf(ls[cq + 2][px]);
  v.w = f2bf(ls[cq + 3][px]);
  *(ushort4*)&xh[((size_t)(b * HW) + p0 + px) * CC + c0 + cq] = v;
}

// ---- pack all 4 weight tensors -> fragment-line layouts ----
__global__ void pack_all(const float* __restrict__ wd1, const float* __restrict__ wo1,
                         const float* __restrict__ wd2, const float* __restrict__ wo2,
                         unsigned short* __restrict__ wpk1, unsigned short* __restrict__ wopk1,
                         unsigned short* __restrict__ wpk2, unsigned short* __restrict__ wopk2) {
  int i = blockIdx.x * 256 + threadIdx.x;   // 368640
  if (i < 294912) {
    int ii = (i < 147456) ? i : i - 147456;
    const float* src = (i < 147456) ? wd1 : wd2;
    unsigned short* dst = (i < 147456) ? wpk1 : wpk2;
    int j = ii & 7, lane = (ii >> 3) & 63, ks = (ii >> 9) & 3, mo = (ii >> 11) & 7, k2 = ii >> 14;
    int o = mo * 16 + (lane & 15), c = ks * 32 + ((lane >> 4) << 3) + j;
    dst[ii] = f2bf(src[(o * CC + c) * 9 + k2]);
  } else {
    int ii = i - 294912;   // 0..73727
    const float* src = (ii < 36864) ? wo1 : wo2;
    unsigned short* dst = (ii < 36864) ? wopk1 : wopk2;
    ii = (ii < 36864) ? ii : ii - 36864;
    int j = ii & 7, lane = (ii >> 3) & 63, ks = (ii >> 9) & 3, mo = (ii >> 11) & 1, k2 = ii >> 12;
    int o = mo * 16 + (lane & 15), c = ks * 32 + ((lane >> 4) << 3) + j;
    dst[ii] = (o < 18) ? f2bf(src[(o * CC + c) * 9 + k2]) : (unsigned short)0;
  }
}

// ---- offset conv via MFMA: 32-px tile, commit-late schedule ----
__global__ __launch_bounds__(256) void offset_mfma(
    const unsigned short* __restrict__ xh, const unsigned short* __restrict__ wopk,
    const float* __restrict__ boff, float* __restrict__ offs2) {
  const int bid0 = blockIdx.x;
  const int bid = (bid0 & 7) * 196 + (bid0 >> 3);   // XCD swizzle, 1568%8==0
  const int b = bid / 392;
  const int p0 = (bid % 392) * 32;
  const int tid = threadIdx.x;
  const int l = tid & 63, w = tid >> 6;
  const int hl = l & 15, ph = l >> 4;
  const int row = l & 15, grp = l >> 4;
  const int pxg = (w >> 1) * 16;    // MFMA pixel-group base
  const int mw = w & 1;             // owned m-fragment
  __shared__ unsigned short s_smp[2][4096];
  const unsigned short* xb = xh + (size_t)b * HW * CC + hl * 8;
  f32x4 acc = (f32x4){0.f, 0.f, 0.f, 0.f};
  uint4 g2[2];
  bf16x8 af[4];

#define OISSUE(K2T)                                                            \
  {                                                                            \
    int ky = (K2T) / 3, kx = (K2T) % 3;                                        \
    _Pragma("unroll") for (int s = 0; s < 2; s++) {                            \
      int pxl = w * 8 + s * 4 + ph;                                            \
      int p = p0 + pxl;                                                        \
      int ho = p / 112, wo = p - ho * 112;                                     \
      int y = ho + ky - 1, x = wo + kx - 1;                                    \
      uint4 t = make_uint4(0u, 0u, 0u, 0u);                                    \
      if (((unsigned)y < 112u) & ((unsigned)x < 112u))                         \
        t = *(const uint4*)&xb[(size_t)(y * 112 + x) * CC];                    \
      g2[s] = t;                                                               \
    }                                                                          \
  }

#define OCOMMIT(BNBUF)                                                         \
  _Pragma("unroll") for (int s = 0; s < 2; s++) {                              \
    int pxl = w * 8 + s * 4 + ph;                                              \
    *(uint4*)((char*)&s_smp[BNBUF][0] +                                        \
              ((pxl * 256 + hl * 16) ^ ((pxl & 7) << 4))) = g2[s];             \
  }

#define OMFMA(BCBUF, ksB)                                                      \
  __builtin_amdgcn_s_setprio(1);                                               \
  _Pragma("unroll") for (int ks = ksB; ks < ksB + 2; ks++) {                   \
    int pxr = pxg + row;                                                       \
    bf16x8 bfr = *(const bf16x8*)((const char*)&s_smp[BCBUF][0] +              \
                 ((pxr * 256 + ks * 64 + grp * 16) ^ ((pxr & 7) << 4)));       \
    acc = __builtin_amdgcn_mfma_f32_16x16x32_bf16(af[ks], bfr, acc, 0, 0, 0);  \
  }                                                                            \
  __builtin_amdgcn_s_setprio(0);

#define OLOADW(K2T)                                                            \
  {                                                                            \
    const unsigned short* wb = wopk + (size_t)(K2T) * 4096;                    \
    _Pragma("unroll") for (int ks = 0; ks < 4; ks++)                           \
      af[ks] = *(const bf16x8*)&wb[(mw * 4 + ks) * 512 + l * 8];               \
  }

#define OITER(K2T, BC, BN)                                                     \
  {                                                                            \
    if ((K2T) < 8) { OISSUE((K2T) + 1); }                                      \
    OMFMA(BC, 0);                                                              \
    OMFMA(BC, 2);                                                              \
    if ((K2T) < 8) { OLOADW((K2T) + 1); OCOMMIT(BN); __syncthreads(); }        \
  }

  OISSUE(0); OCOMMIT(0); OLOADW(0);
  __syncthreads();
  OITER(0, 0, 1) OITER(1, 1, 0) OITER(2, 0, 1) OITER(3, 1, 0) OITER(4, 0, 1)
  OITER(5, 1, 0) OITER(6, 0, 1) OITER(7, 1, 0) OITER(8, 0, 1)
#undef OISSUE
#undef OCOMMIT
#undef OMFMA
#undef OLOADW
#undef OITER

  int p = p0 + pxg + row;
  if (mw == 0) {
    float2 w0 = make_float2(acc[0] + boff[grp * 4 + 0], acc[1] + boff[grp * 4 + 1]);
    float2 w1 = make_float2(acc[2] + boff[grp * 4 + 2], acc[3] + boff[grp * 4 + 3]);
    *(float2*)&offs2[((size_t)(b * 9 + grp * 2) * HW + p) * 2] = w0;
    *(float2*)&offs2[((size_t)(b * 9 + grp * 2 + 1) * HW + p) * 2] = w1;
  } else if (grp == 0) {
    float2 w2 = make_float2(acc[0] + boff[16], acc[1] + boff[17]);
    *(float2*)&offs2[((size_t)(b * 9 + 8) * HW + p) * 2] = w2;
  }
}

// ---- deformable conv via MFMA: 32-px tile (R11 winner), commit-late schedule ----
__global__ __launch_bounds__(256, 3) void deform_mfma(
    const unsigned short* __restrict__ xh, const float* __restrict__ offs2,
    const unsigned short* __restrict__ wpk, unsigned short* __restrict__ zh,
    float* __restrict__ part) {
  const int bid0 = blockIdx.x;
  const int bid = (bid0 & 7) * 196 + (bid0 >> 3);   // XCD swizzle, 1568%8==0
  const int b = bid / 392;
  const int p0 = (bid % 392) * 32;
  const int tid = threadIdx.x;
  const int l = tid & 63, w = tid >> 6;
  const int hl = l & 15, ph = l >> 4;
  const int row = l & 15, grp = l >> 4;
  __shared__ unsigned short s_smp[2][4096];       // 16384 B (32px x 128ch, dbuf)
  __shared__ uint4 s_coord[9][32];                //  4608 B

  // coord precompute: clamped u16 corner indices + bf16 corner weights
  for (int e = tid; e < 288; e += 256) {
    int k2 = e >> 5, px = e & 31;
    int p = p0 + px;
    int ho = p / 112, wo = p - ho * 112;
    int ky = k2 / 3, kx = k2 - 3 * ky;
    float2 dv = *(const float2*)&offs2[((size_t)(b * 9 + k2) * HW + p) * 2];
    float py = (float)(ho + ky - 1) + dv.x;
    float pxf = (float)(wo + kx - 1) + dv.y;
    float y0f = floorf(py), x0f = floorf(pxf);
    float wy = py - y0f, wx = pxf - x0f;
    int y0 = (int)y0f, x0 = (int)x0f;
    int y1 = y0 + 1, x1 = x0 + 1;
    bool iy0 = ((unsigned)y0 < 112u), iy1 = ((unsigned)y1 < 112u);
    bool ix0 = ((unsigned)x0 < 112u), ix1 = ((unsigned)x1 < 112u);
    float v00 = (iy0 & ix0) ? (1.f - wy) * (1.f - wx) : 0.f;
    float v01 = (iy0 & ix1) ? (1.f - wy) * wx : 0.f;
    float v10 = (iy1 & ix0) ? wy * (1.f - wx) : 0.f;
    float v11 = (iy1 & ix1) ? wy * wx : 0.f;
    int y0c = min(max(y0, 0), 111), y1c = min(max(y1, 0), 111);
    int x0c = min(max(x0, 0), 111), x1c = min(max(x1, 0), 111);
    uint4 ce;
    ce.x = (unsigned)(y0c * 112 + x0c) | ((unsigned)(y0c * 112 + x1c) << 16);
    ce.y = (unsigned)(y1c * 112 + x0c) | ((unsigned)(y1c * 112 + x1c) << 16);
    ce.z = (unsigned)f2bf(v00) | ((unsigned)f2bf(v01) << 16);
    ce.w = (unsigned)f2bf(v10) | ((unsigned)f2bf(v11) << 16);
    s_coord[k2][px] = ce;
  }

  const unsigned short* xb = xh + (size_t)b * HW * CC + hl * 8;
  f32x4 acc[2][2];
#pragma unroll
  for (int m = 0; m < 2; m++)
#pragma unroll
    for (int n = 0; n < 2; n++) acc[m][n] = (f32x4){0.f, 0.f, 0.f, 0.f};
  uint4 g[2][4];
  uint2 wts[2];
  bf16x8 af[2][4];
  __syncthreads();

#define DISSUE(K2T)                                                            \
  _Pragma("unroll") for (int s = 0; s < 2; s++) {                              \
    int pxl = w * 8 + s * 4 + ph;                                              \
    uint4 cc = s_coord[K2T][pxl];                                              \
    wts[s] = make_uint2(cc.z, cc.w);                                           \
    g[s][0] = *(const uint4*)&xb[(size_t)(cc.x & 0xffffu) * CC];               \
    g[s][1] = *(const uint4*)&xb[(size_t)(cc.x >> 16) * CC];                   \
    g[s][2] = *(const uint4*)&xb[(size_t)(cc.y & 0xffffu) * CC];               \
    g[s][3] = *(const uint4*)&xb[(size_t)(cc.y >> 16) * CC];                   \
  }

#define DCOMMIT(BNBUF)                                                         \
  _Pragma("unroll") for (int s = 0; s < 2; s++) {                              \
    int pxl = w * 8 + s * 4 + ph;                                              \
    float w00 = bf2f(wts[s].x & 0xffffu), w01 = bf2f(wts[s].x >> 16);          \
    float w10 = bf2f(wts[s].y & 0xffffu), w11 = bf2f(wts[s].y >> 16);          \
    unsigned rr[4];                                                            \
    _Pragma("unroll") for (int q = 0; q < 4; q++) {                            \
      unsigned a0 = uc4(g[s][0], q), a1 = uc4(g[s][1], q);                     \
      unsigned a2 = uc4(g[s][2], q), a3 = uc4(g[s][3], q);                     \
      float elo = w00 * bf2f(a0 & 0xffffu) + w01 * bf2f(a1 & 0xffffu)          \
                + w10 * bf2f(a2 & 0xffffu) + w11 * bf2f(a3 & 0xffffu);         \
      float ehi = w00 * bf2f(a0 >> 16) + w01 * bf2f(a1 >> 16)                  \
                + w10 * bf2f(a2 >> 16) + w11 * bf2f(a3 >> 16);                 \
      rr[q] = (unsigned)f2bf(elo) | ((unsigned)f2bf(ehi) << 16);               \
    }                                                                          \
    *(uint4*)((char*)&s_smp[BNBUF][0] +                                        \
              ((pxl * 256 + hl * 16) ^ ((pxl & 7) << 4))) =                    \
        make_uint4(rr[0], rr[1], rr[2], rr[3]);                                \
  }

#define DMFMA(BCBUF, ksB)                                                      \
  __builtin_amdgcn_s_setprio(1);                                               \
  _Pragma("unroll") for (int ks = ksB; ks < ksB + 2; ks++) {                   \
    bf16x8 bfr[2];                                                             \
    _Pragma("unroll") for (int n = 0; n < 2; n++) {                            \
      int pxr = n * 16 + row;                                                  \
      bfr[n] = *(const bf16x8*)((const char*)&s_smp[BCBUF][0] +                \
               ((pxr * 256 + ks * 64 + grp * 16) ^ ((pxr & 7) << 4)));         \
    }                                                                          \
    _Pragma("unroll") for (int m = 0; m < 2; m++)                              \
      _Pragma("unroll") for (int n = 0; n < 2; n++)                            \
        acc[m][n] = __builtin_amdgcn_mfma_f32_16x16x32_bf16(af[m][ks], bfr[n], acc[m][n], 0, 0, 0); \
  }                                                                            \
  __builtin_amdgcn_s_setprio(0);

#define DLOADW(K2T)                                                            \
  {                                                                            \
    const unsigned short* wb = wpk + (size_t)((K2T) * 8 + w * 2) * 2048;       \
    _Pragma("unroll") for (int m = 0; m < 2; m++)                              \
      _Pragma("unroll") for (int ks = 0; ks < 4; ks++)                         \
        af[m][ks] = *(const bf16x8*)&wb[(m * 4 + ks) * 512 + l * 8];           \
  }

#define DITER(K2T, BC, BN)                                                     \
  {                                                                            \
    if ((K2T) < 8) { DISSUE((K2T) + 1); }                                      \
    DMFMA(BC, 0);                                                              \
    DMFMA(BC, 2);                                                              \
    if ((K2T) < 8) { DLOADW((K2T) + 1); DCOMMIT(BN); __syncthreads(); }        \
  }

  DISSUE(0); DCOMMIT(0); DLOADW(0);
  __syncthreads();
  DITER(0, 0, 1) DITER(1, 1, 0) DITER(2, 0, 1) DITER(3, 1, 0) DITER(4, 0, 1)
  DITER(5, 1, 0) DITER(6, 0, 1) DITER(7, 1, 0) DITER(8, 0, 1)
#undef DISSUE
#undef DCOMMIT
#undef DMFMA
#undef DLOADW
#undef DITER

  // z write (bf16 NHWC)
#pragma unroll
  for (int m = 0; m < 2; m++)
#pragma unroll
    for (int n = 0; n < 2; n++) {
      int o = (w * 2 + m) * 16 + grp * 4;
      size_t px = (size_t)(b * HW) + p0 + n * 16 + row;
      unsigned lo = (unsigned)f2bf(acc[m][n][0]) | ((unsigned)f2bf(acc[m][n][1]) << 16);
      unsigned hi = (unsigned)f2bf(acc[m][n][2]) | ((unsigned)f2bf(acc[m][n][3]) << 16);
      *(uint2*)&zh[px * CC + o] = make_uint2(lo, hi);
    }

  // fused BN partials: per-channel sum/sumsq over this block's 32 px
  float sv[8], qv[8];
#pragma unroll
  for (int m = 0; m < 2; m++)
#pragma unroll
    for (int r = 0; r < 4; r++) {
      float s = 0.f, q = 0.f;
#pragma unroll
      for (int n = 0; n < 2; n++) { float v = acc[m][n][r]; s += v; q += v * v; }
      sv[m * 4 + r] = s; qv[m * 4 + r] = q;
    }
#pragma unroll
  for (int d = 1; d < 16; d <<= 1)
#pragma unroll
    for (int i = 0; i < 8; i++) {
      sv[i] += __shfl_xor(sv[i], d);
      qv[i] += __shfl_xor(qv[i], d);
    }
  if (row == 0) {
#pragma unroll
    for (int m = 0; m < 2; m++)
#pragma unroll
      for (int r = 0; r < 4; r++) {
        int ch = (w * 2 + m) * 16 + grp * 4 + r;
        part[(size_t)ch * 1568 + bid] = sv[m * 4 + r];
        part[(size_t)(128 + ch) * 1568 + bid] = qv[m * 4 + r];
      }
  }
}

// ---- BN stats: reduce 1568 block partials per channel ----
__global__ __launch_bounds__(256) void bn_fin(const float* __restrict__ part,
                                              const float* __restrict__ gamma,
                                              const float* __restrict__ beta,
                                              float* __restrict__ stats) {
  const int c = blockIdx.x, t = threadIdx.x;
  float s = 0.f, q = 0.f;
  for (int j = t; j < 1568; j += 256) {
    s += part[(size_t)c * 1568 + j];
    q += part[(size_t)(128 + c) * 1568 + j];
  }
  __shared__ float ss[256], sq2[256];
  ss[t] = s; sq2[t] = q;
  __syncthreads();
  for (int d = 128; d > 0; d >>= 1) {
    if (t < d) { ss[t] += ss[t + d]; sq2[t] += sq2[t + d]; }
    __syncthreads();
  }
  if (t == 0) {
    float N = 50176.f;
    float m = ss[0] / N;
    float var = sq2[0] / N - m * m;
    stats[c] = m;
    stats[128 + c] = rsqrtf(var + 1e-5f) * gamma[c];
    stats[256 + c] = beta[c];
  }
}

// ---- BN+GELU, z bf16 NHWC -> y bf16 NHWC (feeds block 2) ----
__global__ __launch_bounds__(256) void bn_gelu_to_bf16(
    const unsigned short* __restrict__ zh, const float* __restrict__ stats,
    unsigned short* __restrict__ yh) {
  int i = blockIdx.x * 256 + threadIdx.x;   // 802816 exact
  int c0 = (i & 15) * 8;
  uint4 zv = ((const uint4*)zh)[i];
  f32x4 m0 = *(const f32x4*)&stats[c0], m1 = *(const f32x4*)&stats[c0 + 4];
  f32x4 r0 = *(const f32x4*)&stats[128 + c0], r1 = *(const f32x4*)&stats[128 + c0 + 4];
  f32x4 b0 = *(const f32x4*)&stats[256 + c0], b1 = *(const f32x4*)&stats[256 + c0 + 4];
  float v[8] = {bf2f(zv.x & 0xffffu), bf2f(zv.x >> 16), bf2f(zv.y & 0xffffu), bf2f(zv.y >> 16),
                bf2f(zv.z & 0xffffu), bf2f(zv.z >> 16), bf2f(zv.w & 0xffffu), bf2f(zv.w >> 16)};
  unsigned o[4];
#pragma unroll
  for (int j = 0; j < 4; j++) {
    float mj0 = (j < 2) ? m0[j * 2] : m1[j * 2 - 4], mj1 = (j < 2) ? m0[j * 2 + 1] : m1[j * 2 - 3];
    float rj0 = (j < 2) ? r0[j * 2] : r1[j * 2 - 4], rj1 = (j < 2) ? r0[j * 2 + 1] : r1[j * 2 - 3];
    float bj0 = (j < 2) ? b0[j * 2] : b1[j * 2 - 4], bj1 = (j < 2) ? b0[j * 2 + 1] : b1[j * 2 - 3];
    float e0 = gelu((v[j * 2] - mj0) * rj0 + bj0);
    float e1 = gelu((v[j * 2 + 1] - mj1) * rj1 + bj1);
    o[j] = (unsigned)f2bf(e0) | ((unsigned)f2bf(e1) << 16);
  }
  ((uint4*)yh)[i] = make_uint4(o[0], o[1], o[2], o[3]);
}

// ---- final: BN+GELU on z2 bf16 NHWC, transpose to NCHW, +residual x ----
__global__ __launch_bounds__(256) void bn_gelu_final(
    const unsigned short* __restrict__ zh, const float* __restrict__ stats,
    const float* __restrict__ x, float* __restrict__ out) {
  const int pt = blockIdx.x, b = blockIdx.y;
  const int p0 = pt * 16;
  const int tid = threadIdx.x;
  __shared__ float ls[16][129];
  {
    int cq = tid & 15, r = tid >> 4;
    uint4 zv = *(const uint4*)&zh[((size_t)(b * HW) + p0 + r) * CC + cq * 8];
    float v[8] = {bf2f(zv.x & 0xffffu), bf2f(zv.x >> 16), bf2f(zv.y & 0xffffu), bf2f(zv.y >> 16),
                  bf2f(zv.z & 0xffffu), bf2f(zv.z >> 16), bf2f(zv.w & 0xffffu), bf2f(zv.w >> 16)};
    f32x4 m0 = *(const f32x4*)&stats[cq * 8], m1 = *(const f32x4*)&stats[cq * 8 + 4];
    f32x4 r0 = *(const f32x4*)&stats[128 + cq * 8], r1 = *(const f32x4*)&stats[128 + cq * 8 + 4];
    f32x4 b0 = *(const f32x4*)&stats[256 + cq * 8], b1 = *(const f32x4*)&stats[256 + cq * 8 + 4];
#pragma unroll
    for (int j = 0; j < 4; j++) {
      ls[r][cq * 8 + j] = gelu((v[j] - m0[j]) * r0[j] + b0[j]);
      ls[r][cq * 8 + 4 + j] = gelu((v[4 + j] - m1[j]) * r1[j] + b1[j]);
    }
  }
  __syncthreads();
  int c = tid & 127, half = tid >> 7;
  const float* xr = x + ((size_t)(b * CC) + c) * HW + p0 + half * 8;
  float* orow = out + ((size_t)(b * CC) + c) * HW + p0 + half * 8;
  float4 o1 = make_float4(ls[half * 8 + 0][c], ls[half * 8 + 1][c],
                          ls[half * 8 + 2][c], ls[half * 8 + 3][c]);
  float4 o2 = make_float4(ls[half * 8 + 4][c], ls[half * 8 + 5][c],
                          ls[half * 8 + 6][c], ls[half * 8 + 7][c]);
  float4 x1 = *(const float4*)&xr[0];
  float4 x2 = *(const float4*)&xr[4];
  o1.x += x1.x; o1.y += x1.y; o1.z += x1.z; o1.w += x1.w;
  o2.x += x2.x; o2.y += x2.y; o2.z += x2.z; o2.w += x2.w;
  *(float4*)&orow[0] = o1;
  *(float4*)&orow[4] = o2;
}

extern "C" void kernel_launch(void* const* d_in, const int* in_sizes, int n_in,
                              void* d_out, int out_size, void* d_ws, size_t ws_size,
                              hipStream_t stream) {
  const float* x = (const float*)d_in[0];
  const float* w_off1 = (const float*)d_in[1];
  const float* b_off1 = (const float*)d_in[2];
  const float* w_def1 = (const float*)d_in[3];
  const float* gamma1 = (const float*)d_in[4];
  const float* beta1 = (const float*)d_in[5];
  const float* w_off2 = (const float*)d_in[6];
  const float* b_off2 = (const float*)d_in[7];
  const float* w_def2 = (const float*)d_in[8];
  const float* gamma2 = (const float*)d_in[9];
  const float* beta2 = (const float*)d_in[10];
  float* out = (float*)d_out;

  char* ws = (char*)d_ws;
  unsigned short* xhb = (unsigned short*)ws;                  // 12,845,056 B (x NHWC bf16, later y1h)
  unsigned short* zhb = (unsigned short*)(ws + 12845056);     // 12,845,056 B (z bf16 NHWC)
  float* offb = (float*)(ws + 25690112);                      //  3,612,672 B
  unsigned short* wpk1 = (unsigned short*)(ws + 29302784);    //    294,912 B
  unsigned short* wpk2 = (unsigned short*)(ws + 29597696);    //    294,912 B
  unsigned short* wopk1 = (unsigned short*)(ws + 29892608);   //     73,728 B
  unsigned short* wopk2 = (unsigned short*)(ws + 29966336);   //     73,728 B
  float* partb = (float*)(ws + 30040064);                     //  1,605,632 B (256 ch x 1568)
  float* statsb = (float*)(ws + 31645696);                    //      1,536 B

  to_nhwc<<<dim3(392, 4, 4), 256, 0, stream>>>(x, xhb);
  pack_all<<<1440, 256, 0, stream>>>(w_def1, w_off1, w_def2, w_off2,
                                     wpk1, wopk1, wpk2, wopk2);

  // ---- block 1 ----
  offset_mfma<<<1568, 256, 0, stream>>>(xhb, wopk1, b_off1, offb);
  deform_mfma<<<1568, 256, 0, stream>>>(xhb, offb, wpk1, zhb, partb);
  bn_fin<<<128, 256, 0, stream>>>(partb, gamma1, beta1, statsb);
  bn_gelu_to_bf16<<<3136, 256, 0, stream>>>(zhb, statsb, xhb);

  // ---- block 2 ----
  offset_mfma<<<1568, 256, 0, stream>>>(xhb, wopk2, b_off2, offb);
  deform_mfma<<<1568, 256, 0, stream>>>(xhb, offb, wpk2, zhb, partb);
  bn_fin<<<128, 256, 0, stream>>>(partb, gamma2, beta2, statsb);
  bn_gelu_final<<<dim3(784, 4), 256, 0, stream>>>(zhb, statsb, x, out);
}

// Round 16
// 171.504 us; speedup vs baseline: 1.1360x; 1.0013x over previous
//
#include <hip/hip_runtime.h>
#include <hip/hip_bf16.h>
#include <math.h>

#define HW 12544
#define CC 128
#define BB 4

typedef short bf16x8 __attribute__((ext_vector_type(8)));
typedef float f32x4 __attribute__((ext_vector_type(4)));

__device__ __forceinline__ float bf2f(unsigned int u) {
  union { unsigned int i; float f; } v; v.i = u << 16; return v.f;
}
__device__ __forceinline__ unsigned short f2bf(float f) {
  __hip_bfloat16 h = __float2bfloat16(f);
  return *reinterpret_cast<unsigned short*>(&h);
}
__device__ __forceinline__ float gelu(float v) {
  return 0.5f * v * (1.f + erff(v * 0.70710678118654752f));
}
__device__ __forceinline__ unsigned uc4(const uint4& v, int q) {
  return q == 0 ? v.x : q == 1 ? v.y : q == 2 ? v.z : v.w;
}

// ---- x NCHW fp32 -> xh NHWC bf16 ----
__global__ __launch_bounds__(256) void to_nhwc(const float* __restrict__ x,
                                               unsigned short* __restrict__ xh) {
  const int pt = blockIdx.x, ct = blockIdx.y, b = blockIdx.z;
  const int p0 = pt * 32, c0 = ct * 32;
  const int tid = threadIdx.x;
  __shared__ float ls[32][33];
  int col = tid & 31, r = tid >> 5;
#pragma unroll
  for (int i = 0; i < 4; i++) {
    int c = c0 + r + i * 8;
    ls[r + i * 8][col] = x[((size_t)(b * CC) + c) * HW + p0 + col];
  }
  __syncthreads();
  int px = tid >> 3, cq = (tid & 7) * 4;
  ushort4 v;
  v.x = f2bf(ls[cq + 0][px]);
  v.y = f2bf(ls[cq + 1][px]);
  v.z = f2bf(ls[cq + 2][px]);
  v.w = f2bf(ls[cq + 3][px]);
  *(ushort4*)&xh[((size_t)(b * HW) + p0 + px) * CC + c0 + cq] = v;
}

// ---- pack all 4 weight tensors -> fragment-line layouts ----
__global__ void pack_all(const float* __restrict__ wd1, const float* __restrict__ wo1,
                         const float* __restrict__ wd2, const float* __restrict__ wo2,
                         unsigned short* __restrict__ wpk1, unsigned short* __restrict__ wopk1,
                         unsigned short* __restrict__ wpk2, unsigned short* __restrict__ wopk2) {
  int i = blockIdx.x * 256 + threadIdx.x;   // 368640
  if (i < 294912) {
    int ii = (i < 147456) ? i : i - 147456;
    const float* src = (i < 147456) ? wd1 : wd2;
    unsigned short* dst = (i < 147456) ? wpk1 : wpk2;
    int j = ii & 7, lane = (ii >> 3) & 63, ks = (ii >> 9) & 3, mo = (ii >> 11) & 7, k2 = ii >> 14;
    int o = mo * 16 + (lane & 15), c = ks * 32 + ((lane >> 4) << 3) + j;
    dst[ii] = f2bf(src[(o * CC + c) * 9 + k2]);
  } else {
    int ii = i - 294912;   // 0..73727
    const float* src = (ii < 36864) ? wo1 : wo2;
    unsigned short* dst = (ii < 36864) ? wopk1 : wopk2;
    ii = (ii < 36864) ? ii : ii - 36864;
    int j = ii & 7, lane = (ii >> 3) & 63, ks = (ii >> 9) & 3, mo = (ii >> 11) & 1, k2 = ii >> 12;
    int o = mo * 16 + (lane & 15), c = ks * 32 + ((lane >> 4) << 3) + j;
    dst[ii] = (o < 18) ? f2bf(src[(o * CC + c) * 9 + k2]) : (unsigned short)0;
  }
}

// ---- offset conv via MFMA: 32-px tile, commit-late schedule ----
__global__ __launch_bounds__(256) void offset_mfma(
    const unsigned short* __restrict__ xh, const unsigned short* __restrict__ wopk,
    const float* __restrict__ boff, float* __restrict__ offs2) {
  const int bid0 = blockIdx.x;
  const int bid = (bid0 & 7) * 196 + (bid0 >> 3);   // XCD swizzle, 1568%8==0
  const int b = bid / 392;
  const int p0 = (bid % 392) * 32;
  const int tid = threadIdx.x;
  const int l = tid & 63, w = tid >> 6;
  const int hl = l & 15, ph = l >> 4;
  const int row = l & 15, grp = l >> 4;
  const int pxg = (w >> 1) * 16;    // MFMA pixel-group base
  const int mw = w & 1;             // owned m-fragment
  __shared__ unsigned short s_smp[2][4096];
  const unsigned short* xb = xh + (size_t)b * HW * CC + hl * 8;
  f32x4 acc = (f32x4){0.f, 0.f, 0.f, 0.f};
  uint4 g2[2];
  bf16x8 af[4];

#define OISSUE(K2T)                                                            \
  {                                                                            \
    int ky = (K2T) / 3, kx = (K2T) % 3;                                        \
    _Pragma("unroll") for (int s = 0; s < 2; s++) {                            \
      int pxl = w * 8 + s * 4 + ph;                                            \
      int p = p0 + pxl;                                                        \
      int ho = p / 112, wo = p - ho * 112;                                     \
      int y = ho + ky - 1, x = wo + kx - 1;                                    \
      uint4 t = make_uint4(0u, 0u, 0u, 0u);                                    \
      if (((unsigned)y < 112u) & ((unsigned)x < 112u))                         \
        t = *(const uint4*)&xb[(size_t)(y * 112 + x) * CC];                    \
      g2[s] = t;                                                               \
    }                                                                          \
  }

#define OCOMMIT(BNBUF)                                                         \
  _Pragma("unroll") for (int s = 0; s < 2; s++) {                              \
    int pxl = w * 8 + s * 4 + ph;                                              \
    *(uint4*)((char*)&s_smp[BNBUF][0] +                                        \
              ((pxl * 256 + hl * 16) ^ ((pxl & 7) << 4))) = g2[s];             \
  }

#define OMFMA(BCBUF, ksB)                                                      \
  __builtin_amdgcn_s_setprio(1);                                               \
  _Pragma("unroll") for (int ks = ksB; ks < ksB + 2; ks++) {                   \
    int pxr = pxg + row;                                                       \
    bf16x8 bfr = *(const bf16x8*)((const char*)&s_smp[BCBUF][0] +              \
                 ((pxr * 256 + ks * 64 + grp * 16) ^ ((pxr & 7) << 4)));       \
    acc = __builtin_amdgcn_mfma_f32_16x16x32_bf16(af[ks], bfr, acc, 0, 0, 0);  \
  }                                                                            \
  __builtin_amdgcn_s_setprio(0);

#define OLOADW(K2T)                                                            \
  {                                                                            \
    const unsigned short* wb = wopk + (size_t)(K2T) * 4096;                    \
    _Pragma("unroll") for (int ks = 0; ks < 4; ks++)                           \
      af[ks] = *(const bf16x8*)&wb[(mw * 4 + ks) * 512 + l * 8];               \
  }

#define OITER(K2T, BC, BN)                                                     \
  {                                                                            \
    if ((K2T) < 8) { OISSUE((K2T) + 1); }                                      \
    OMFMA(BC, 0);                                                              \
    OMFMA(BC, 2);                                                              \
    if ((K2T) < 8) { OLOADW((K2T) + 1); OCOMMIT(BN); __syncthreads(); }        \
  }

  OISSUE(0); OCOMMIT(0); OLOADW(0);
  __syncthreads();
  OITER(0, 0, 1) OITER(1, 1, 0) OITER(2, 0, 1) OITER(3, 1, 0) OITER(4, 0, 1)
  OITER(5, 1, 0) OITER(6, 0, 1) OITER(7, 1, 0) OITER(8, 0, 1)
#undef OISSUE
#undef OCOMMIT
#undef OMFMA
#undef OLOADW
#undef OITER

  int p = p0 + pxg + row;
  if (mw == 0) {
    float2 w0 = make_float2(acc[0] + boff[grp * 4 + 0], acc[1] + boff[grp * 4 + 1]);
    float2 w1 = make_float2(acc[2] + boff[grp * 4 + 2], acc[3] + boff[grp * 4 + 3]);
    *(float2*)&offs2[((size_t)(b * 9 + grp * 2) * HW + p) * 2] = w0;
    *(float2*)&offs2[((size_t)(b * 9 + grp * 2 + 1) * HW + p) * 2] = w1;
  } else if (grp == 0) {
    float2 w2 = make_float2(acc[0] + boff[16], acc[1] + boff[17]);
    *(float2*)&offs2[((size_t)(b * 9 + 8) * HW + p) * 2] = w2;
  }
}

// ---- deformable conv via MFMA: 32-px tile (R11 winner), commit-late schedule ----
__global__ __launch_bounds__(256, 3) void deform_mfma(
    const unsigned short* __restrict__ xh, const float* __restrict__ offs2,
    const unsigned short* __restrict__ wpk, unsigned short* __restrict__ zh,
    float* __restrict__ part) {
  const int bid0 = blockIdx.x;
  const int bid = (bid0 & 7) * 196 + (bid0 >> 3);   // XCD swizzle, 1568%8==0
  const int b = bid / 392;
  const int p0 = (bid % 392) * 32;
  const int tid = threadIdx.x;
  const int l = tid & 63, w = tid >> 6;
  const int hl = l & 15, ph = l >> 4;
  const int row = l & 15, grp = l >> 4;
  __shared__ unsigned short s_smp[2][4096];       // 16384 B (32px x 128ch, dbuf)
  __shared__ uint4 s_coord[9][32];                //  4608 B

  // coord precompute: clamped u16 corner indices + bf16 corner weights
  for (int e = tid; e < 288; e += 256) {
    int k2 = e >> 5, px = e & 31;
    int p = p0 + px;
    int ho = p / 112, wo = p - ho * 112;
    int ky = k2 / 3, kx = k2 - 3 * ky;
    float2 dv = *(const float2*)&offs2[((size_t)(b * 9 + k2) * HW + p) * 2];
    float py = (float)(ho + ky - 1) + dv.x;
    float pxf = (float)(wo + kx - 1) + dv.y;
    float y0f = floorf(py), x0f = floorf(pxf);
    float wy = py - y0f, wx = pxf - x0f;
    int y0 = (int)y0f, x0 = (int)x0f;
    int y1 = y0 + 1, x1 = x0 + 1;
    bool iy0 = ((unsigned)y0 < 112u), iy1 = ((unsigned)y1 < 112u);
    bool ix0 = ((unsigned)x0 < 112u), ix1 = ((unsigned)x1 < 112u);
    float v00 = (iy0 & ix0) ? (1.f - wy) * (1.f - wx) : 0.f;
    float v01 = (iy0 & ix1) ? (1.f - wy) * wx : 0.f;
    float v10 = (iy1 & ix0) ? wy * (1.f - wx) : 0.f;
    float v11 = (iy1 & ix1) ? wy * wx : 0.f;
    int y0c = min(max(y0, 0), 111), y1c = min(max(y1, 0), 111);
    int x0c = min(max(x0, 0), 111), x1c = min(max(x1, 0), 111);
    uint4 ce;
    ce.x = (unsigned)(y0c * 112 + x0c) | ((unsigned)(y0c * 112 + x1c) << 16);
    ce.y = (unsigned)(y1c * 112 + x0c) | ((unsigned)(y1c * 112 + x1c) << 16);
    ce.z = (unsigned)f2bf(v00) | ((unsigned)f2bf(v01) << 16);
    ce.w = (unsigned)f2bf(v10) | ((unsigned)f2bf(v11) << 16);
    s_coord[k2][px] = ce;
  }

  const unsigned short* xb = xh + (size_t)b * HW * CC + hl * 8;
  f32x4 acc[2][2];
#pragma unroll
  for (int m = 0; m < 2; m++)
#pragma unroll
    for (int n = 0; n < 2; n++) acc[m][n] = (f32x4){0.f, 0.f, 0.f, 0.f};
  uint4 g[2][4];
  uint2 wts[2];
  bf16x8 af[2][4];
  __syncthreads();

#define DISSUE(K2T)                                                            \
  _Pragma("unroll") for (int s = 0; s < 2; s++) {                              \
    int pxl = w * 8 + s * 4 + ph;                                              \
    uint4 cc = s_coord[K2T][pxl];                                              \
    wts[s] = make_uint2(cc.z, cc.w);                                           \
    g[s][0] = *(const uint4*)&xb[(size_t)(cc.x & 0xffffu) * CC];               \
    g[s][1] = *(const uint4*)&xb[(size_t)(cc.x >> 16) * CC];                   \
    g[s][2] = *(const uint4*)&xb[(size_t)(cc.y & 0xffffu) * CC];               \
    g[s][3] = *(const uint4*)&xb[(size_t)(cc.y >> 16) * CC];                   \
  }

#define DCOMMIT(BNBUF)                                                         \
  _Pragma("unroll") for (int s = 0; s < 2; s++) {                              \
    int pxl = w * 8 + s * 4 + ph;                                              \
    float w00 = bf2f(wts[s].x & 0xffffu), w01 = bf2f(wts[s].x >> 16);          \
    float w10 = bf2f(wts[s].y & 0xffffu), w11 = bf2f(wts[s].y >> 16);          \
    unsigned rr[4];                                                            \
    _Pragma("unroll") for (int q = 0; q < 4; q++) {                            \
      unsigned a0 = uc4(g[s][0], q), a1 = uc4(g[s][1], q);                     \
      unsigned a2 = uc4(g[s][2], q), a3 = uc4(g[s][3], q);                     \
      float elo = w00 * bf2f(a0 & 0xffffu) + w01 * bf2f(a1 & 0xffffu)          \
                + w10 * bf2f(a2 & 0xffffu) + w11 * bf2f(a3 & 0xffffu);         \
      float ehi = w00 * bf2f(a0 >> 16) + w01 * bf2f(a1 >> 16)                  \
                + w10 * bf2f(a2 >> 16) + w11 * bf2f(a3 >> 16);                 \
      rr[q] = (unsigned)f2bf(elo) | ((unsigned)f2bf(ehi) << 16);               \
    }                                                                          \
    *(uint4*)((char*)&s_smp[BNBUF][0] +                                        \
              ((pxl * 256 + hl * 16) ^ ((pxl & 7) << 4))) =                    \
        make_uint4(rr[0], rr[1], rr[2], rr[3]);                                \
  }

#define DMFMA(BCBUF, ksB)                                                      \
  __builtin_amdgcn_s_setprio(1);                                               \
  _Pragma("unroll") for (int ks = ksB; ks < ksB + 2; ks++) {                   \
    bf16x8 bfr[2];                                                             \
    _Pragma("unroll") for (int n = 0; n < 2; n++) {                            \
      int pxr = n * 16 + row;                                                  \
      bfr[n] = *(const bf16x8*)((const char*)&s_smp[BCBUF][0] +                \
               ((pxr * 256 + ks * 64 + grp * 16) ^ ((pxr & 7) << 4)));         \
    }                                                                          \
    _Pragma("unroll") for (int m = 0; m < 2; m++)                              \
      _Pragma("unroll") for (int n = 0; n < 2; n++)                            \
        acc[m][n] = __builtin_amdgcn_mfma_f32_16x16x32_bf16(af[m][ks], bfr[n], acc[m][n], 0, 0, 0); \
  }                                                                            \
  __builtin_amdgcn_s_setprio(0);

#define DLOADW(K2T)                                                            \
  {                                                                            \
    const unsigned short* wb = wpk + (size_t)((K2T) * 8 + w * 2) * 2048;       \
    _Pragma("unroll") for (int m = 0; m < 2; m++)                              \
      _Pragma("unroll") for (int ks = 0; ks < 4; ks++)                         \
        af[m][ks] = *(const bf16x8*)&wb[(m * 4 + ks) * 512 + l * 8];           \
  }

#define DITER(K2T, BC, BN)                                                     \
  {                                                                            \
    if ((K2T) < 8) { DISSUE((K2T) + 1); }                                      \
    DMFMA(BC, 0);                                                              \
    DMFMA(BC, 2);                                                              \
    if ((K2T) < 8) { DLOADW((K2T) + 1); DCOMMIT(BN); __syncthreads(); }        \
  }

  DISSUE(0); DCOMMIT(0); DLOADW(0);
  __syncthreads();
  DITER(0, 0, 1) DITER(1, 1, 0) DITER(2, 0, 1) DITER(3, 1, 0) DITER(4, 0, 1)
  DITER(5, 1, 0) DITER(6, 0, 1) DITER(7, 1, 0) DITER(8, 0, 1)
#undef DISSUE
#undef DCOMMIT
#undef DMFMA
#undef DLOADW
#undef DITER

  // z write (bf16 NHWC)
#pragma unroll
  for (int m = 0; m < 2; m++)
#pragma unroll
    for (int n = 0; n < 2; n++) {
      int o = (w * 2 + m) * 16 + grp * 4;
      size_t px = (size_t)(b * HW) + p0 + n * 16 + row;
      unsigned lo = (unsigned)f2bf(acc[m][n][0]) | ((unsigned)f2bf(acc[m][n][1]) << 16);
      unsigned hi = (unsigned)f2bf(acc[m][n][2]) | ((unsigned)f2bf(acc[m][n][3]) << 16);
      *(uint2*)&zh[px * CC + o] = make_uint2(lo, hi);
    }

  // fused BN partials: per-channel sum/sumsq over this block's 32 px
  float sv[8], qv[8];
#pragma unroll
  for (int m = 0; m < 2; m++)
#pragma unroll
    for (int r = 0; r < 4; r++) {
      float s = 0.f, q = 0.f;
#pragma unroll
      for (int n = 0; n < 2; n++) { float v = acc[m][n][r]; s += v; q += v * v; }
      sv[m * 4 + r] = s; qv[m * 4 + r] = q;
    }
#pragma unroll
  for (int d = 1; d < 16; d <<= 1)
#pragma unroll
    for (int i = 0; i < 8; i++) {
      sv[i] += __shfl_xor(sv[i], d);
      qv[i] += __shfl_xor(qv[i], d);
    }
  if (row == 0) {
#pragma unroll
    for (int m = 0; m < 2; m++)
#pragma unroll
      for (int r = 0; r < 4; r++) {
        int ch = (w * 2 + m) * 16 + grp * 4 + r;
        part[(size_t)ch * 1568 + bid] = sv[m * 4 + r];
        part[(size_t)(128 + ch) * 1568 + bid] = qv[m * 4 + r];
      }
  }
}

// ---- BN stats: reduce 1568 block partials per channel ----
__global__ __launch_bounds__(256) void bn_fin(const float* __restrict__ part,
                                              const float* __restrict__ gamma,
                                              const float* __restrict__ beta,
                                              float* __restrict__ stats) {
  const int c = blockIdx.x, t = threadIdx.x;
  float s = 0.f, q = 0.f;
  for (int j = t; j < 1568; j += 256) {
    s += part[(size_t)c * 1568 + j];
    q += part[(size_t)(128 + c) * 1568 + j];
  }
  __shared__ float ss[256], sq2[256];
  ss[t] = s; sq2[t] = q;
  __syncthreads();
  for (int d = 128; d > 0; d >>= 1) {
    if (t < d) { ss[t] += ss[t + d]; sq2[t] += sq2[t + d]; }
    __syncthreads();
  }
  if (t == 0) {
    float N = 50176.f;
    float m = ss[0] / N;
    float var = sq2[0] / N - m * m;
    stats[c] = m;
    stats[128 + c] = rsqrtf(var + 1e-5f) * gamma[c];
    stats[256 + c] = beta[c];
  }
}

// ---- BN+GELU, z bf16 NHWC -> y bf16 NHWC (feeds block 2) ----
__global__ __launch_bounds__(256) void bn_gelu_to_bf16(
    const unsigned short* __restrict__ zh, const float* __restrict__ stats,
    unsigned short* __restrict__ yh) {
  int i = blockIdx.x * 256 + threadIdx.x;   // 802816 exact
  int c0 = (i & 15) * 8;
  uint4 zv = ((const uint4*)zh)[i];
  f32x4 m0 = *(const f32x4*)&stats[c0], m1 = *(const f32x4*)&stats[c0 + 4];
  f32x4 r0 = *(const f32x4*)&stats[128 + c0], r1 = *(const f32x4*)&stats[128 + c0 + 4];
  f32x4 b0 = *(const f32x4*)&stats[256 + c0], b1 = *(const f32x4*)&stats[256 + c0 + 4];
  float v[8] = {bf2f(zv.x & 0xffffu), bf2f(zv.x >> 16), bf2f(zv.y & 0xffffu), bf2f(zv.y >> 16),
                bf2f(zv.z & 0xffffu), bf2f(zv.z >> 16), bf2f(zv.w & 0xffffu), bf2f(zv.w >> 16)};
  unsigned o[4];
#pragma unroll
  for (int j = 0; j < 4; j++) {
    float mj0 = (j < 2) ? m0[j * 2] : m1[j * 2 - 4], mj1 = (j < 2) ? m0[j * 2 + 1] : m1[j * 2 - 3];
    float rj0 = (j < 2) ? r0[j * 2] : r1[j * 2 - 4], rj1 = (j < 2) ? r0[j * 2 + 1] : r1[j * 2 - 3];
    float bj0 = (j < 2) ? b0[j * 2] : b1[j * 2 - 4], bj1 = (j < 2) ? b0[j * 2 + 1] : b1[j * 2 - 3];
    float e0 = gelu((v[j * 2] - mj0) * rj0 + bj0);
    float e1 = gelu((v[j * 2 + 1] - mj1) * rj1 + bj1);
    o[j] = (unsigned)f2bf(e0) | ((unsigned)f2bf(e1) << 16);
  }
  ((uint4*)yh)[i] = make_uint4(o[0], o[1], o[2], o[3]);
}

// ---- final: BN+GELU on z2 bf16 NHWC, transpose to NCHW, +residual x ----
__global__ __launch_bounds__(256) void bn_gelu_final(
    const unsigned short* __restrict__ zh, const float* __restrict__ stats,
    const float* __restrict__ x, float* __restrict__ out) {
  const int pt = blockIdx.x, b = blockIdx.y;
  const int p0 = pt * 16;
  const int tid = threadIdx.x;
  __shared__ float ls[16][129];
  {
    int cq = tid & 15, r = tid >> 4;
    uint4 zv = *(const uint4*)&zh[((size_t)(b * HW) + p0 + r) * CC + cq * 8];
    float v[8] = {bf2f(zv.x & 0xffffu), bf2f(zv.x >> 16), bf2f(zv.y & 0xffffu), bf2f(zv.y >> 16),
                  bf2f(zv.z & 0xffffu), bf2f(zv.z >> 16), bf2f(zv.w & 0xffffu), bf2f(zv.w >> 16)};
    f32x4 m0 = *(const f32x4*)&stats[cq * 8], m1 = *(const f32x4*)&stats[cq * 8 + 4];
    f32x4 r0 = *(const f32x4*)&stats[128 + cq * 8], r1 = *(const f32x4*)&stats[128 + cq * 8 + 4];
    f32x4 b0 = *(const f32x4*)&stats[256 + cq * 8], b1 = *(const f32x4*)&stats[256 + cq * 8 + 4];
#pragma unroll
    for (int j = 0; j < 4; j++) {
      ls[r][cq * 8 + j] = gelu((v[j] - m0[j]) * r0[j] + b0[j]);
      ls[r][cq * 8 + 4 + j] = gelu((v[4 + j] - m1[j]) * r1[j] + b1[j]);
    }
  }
  __syncthreads();
  int c = tid & 127, half = tid >> 7;
  const float* xr = x + ((size_t)(b * CC) + c) * HW + p0 + half * 8;
  float* orow = out + ((size_t)(b * CC) + c) * HW + p0 + half * 8;
  float4 o1 = make_float4(ls[half * 8 + 0][c], ls[half * 8 + 1][c],
                          ls[half * 8 + 2][c], ls[half * 8 + 3][c]);
  float4 o2 = make_float4(ls[half * 8 + 4][c], ls[half * 8 + 5][c],
                          ls[half * 8 + 6][c], ls[half * 8 + 7][c]);
  float4 x1 = *(const float4*)&xr[0];
  float4 x2 = *(const float4*)&xr[4];
  o1.x += x1.x; o1.y += x1.y; o1.z += x1.z; o1.w += x1.w;
  o2.x += x2.x; o2.y += x2.y; o2.z += x2.z; o2.w += x2.w;
  *(float4*)&orow[0] = o1;
  *(float4*)&orow[4] = o2;
}

extern "C" void kernel_launch(void* const* d_in, const int* in_sizes, int n_in,
                              void* d_out, int out_size, void* d_ws, size_t ws_size,
                              hipStream_t stream) {
  const float* x = (const float*)d_in[0];
  const float* w_off1 = (const float*)d_in[1];
  const float* b_off1 = (const float*)d_in[2];
  const float* w_def1 = (const float*)d_in[3];
  const float* gamma1 = (const float*)d_in[4];
  const float* beta1 = (const float*)d_in[5];
  const float* w_off2 = (const float*)d_in[6];
  const float* b_off2 = (const float*)d_in[7];
  const float* w_def2 = (const float*)d_in[8];
  const float* gamma2 = (const float*)d_in[9];
  const float* beta2 = (const float*)d_in[10];
  float* out = (float*)d_out;

  char* ws = (char*)d_ws;
  unsigned short* xhb = (unsigned short*)ws;                  // 12,845,056 B (x NHWC bf16, later y1h)
  unsigned short* zhb = (unsigned short*)(ws + 12845056);     // 12,845,056 B (z bf16 NHWC)
  float* offb = (float*)(ws + 25690112);                      //  3,612,672 B
  unsigned short* wpk1 = (unsigned short*)(ws + 29302784);    //    294,912 B
  unsigned short* wpk2 = (unsigned short*)(ws + 29597696);    //    294,912 B
  unsigned short* wopk1 = (unsigned short*)(ws + 29892608);   //     73,728 B
  unsigned short* wopk2 = (unsigned short*)(ws + 29966336);   //     73,728 B
  float* partb = (float*)(ws + 30040064);                     //  1,605,632 B (256 ch x 1568)
  float* statsb = (float*)(ws + 31645696);                    //      1,536 B

  to_nhwc<<<dim3(392, 4, 4), 256, 0, stream>>>(x, xhb);
  pack_all<<<1440, 256, 0, stream>>>(w_def1, w_off1, w_def2, w_off2,
                                     wpk1, wopk1, wpk2, wopk2);

  // ---- block 1 ----
  offset_mfma<<<1568, 256, 0, stream>>>(xhb, wopk1, b_off1, offb);
  deform_mfma<<<1568, 256, 0, stream>>>(xhb, offb, wpk1, zhb, partb);
  bn_fin<<<128, 256, 0, stream>>>(partb, gamma1, beta1, statsb);
  bn_gelu_to_bf16<<<3136, 256, 0, stream>>>(zhb, statsb, xhb);

  // ---- block 2 ----
  offset_mfma<<<1568, 256, 0, stream>>>(xhb, wopk2, b_off2, offb);
  deform_mfma<<<1568, 256, 0, stream>>>(xhb, offb, wpk2, zhb, partb);
  bn_fin<<<128, 256, 0, stream>>>(partb, gamma2, beta2, statsb);
  bn_gelu_final<<<dim3(784, 4), 256, 0, stream>>>(zhb, statsb, x, out);
}